// Round 1
// baseline (329.914 us; speedup 1.0000x reference)
//
#include <hip/hip_runtime.h>

using short8  = __attribute__((ext_vector_type(8))) short;
using ushort8 = __attribute__((ext_vector_type(8))) unsigned short;
using f32x4   = __attribute__((ext_vector_type(4))) float;

#define T 4096
#define E 1024
#define NB 2
#define BK 32

__device__ __forceinline__ unsigned short f2bf(float f) {
    unsigned int u = __builtin_bit_cast(unsigned int, f);
    u = (u + 0x7FFFu + ((u >> 16) & 1u)) >> 16;
    return (unsigned short)u;
}

__device__ __forceinline__ void gld16(const unsigned short* g, unsigned short* l) {
    __builtin_amdgcn_global_load_lds(
        (__attribute__((address_space(1))) void*)g,
        (__attribute__((address_space(3))) void*)l, 16, 0, 0);
}

__device__ __forceinline__ void do_cvt(const float* __restrict__ src,
                                       unsigned short* __restrict__ dst, int blk) {
    size_t i = ((size_t)blk * 256 + threadIdx.x) * 8;
    float4 f0 = *(const float4*)(src + i);
    float4 f1 = *(const float4*)(src + i + 4);
    ushort8 u;
    u[0]=f2bf(f0.x); u[1]=f2bf(f0.y); u[2]=f2bf(f0.z); u[3]=f2bf(f0.w);
    u[4]=f2bf(f1.x); u[5]=f2bf(f1.y); u[6]=f2bf(f1.z); u[7]=f2bf(f1.w);
    *(ushort8*)(dst + i) = u;
}

__device__ __forceinline__ void do_vt(const float* __restrict__ v,
                                      unsigned short* __restrict__ vt, int id,
                                      float (*tile)[65]) {
    int b   = id / (64 * 16);
    int rem = id % (64 * 16);
    int t0  = (rem / 16) * 64;
    int e0  = (rem % 16) * 64;
    int tid = threadIdx.x;
    int r   = tid >> 2;
    int c0  = (tid & 3) * 16;
    const float* src = v + ((size_t)(b * T + t0 + r)) * E + e0 + c0;
    #pragma unroll
    for (int i = 0; i < 4; i++) {
        float4 f = *(const float4*)(src + i * 4);
        tile[r][c0 + i*4 + 0] = f.x;
        tile[r][c0 + i*4 + 1] = f.y;
        tile[r][c0 + i*4 + 2] = f.z;
        tile[r][c0 + i*4 + 3] = f.w;
    }
    __syncthreads();
    int er = tid >> 2;
    #pragma unroll
    for (int ch = 0; ch < 2; ch++) {
        int tl = (tid & 3) * 16 + ch * 8;
        ushort8 u;
        #pragma unroll
        for (int j = 0; j < 8; j++) u[j] = f2bf(tile[tl + j][er]);
        *(ushort8*)(vt + ((size_t)(b * E + e0 + er)) * T + t0 + tl) = u;
    }
}

// fused prep: [0,4096) q | [4096,8192) k | [8192,10240) v-transpose | [10240,10272) zero lsum
__global__ __launch_bounds__(256) void prep(const float* __restrict__ q,
                                            const float* __restrict__ k,
                                            const float* __restrict__ v,
                                            unsigned short* __restrict__ qb,
                                            unsigned short* __restrict__ kb,
                                            unsigned short* __restrict__ vt,
                                            float* __restrict__ lsum) {
    __shared__ float tile[64][65];
    int bid = blockIdx.x;
    if (bid < 4096)        do_cvt(q, qb, bid);
    else if (bid < 8192)   do_cvt(k, kb, bid - 4096);
    else if (bid < 10240)  do_vt(v, vt, bid - 8192, tile);
    else                   lsum[(bid - 10240) * 256 + threadIdx.x] = 0.0f;
}

// fallback pieces (aliased-ws path)
__global__ __launch_bounds__(256) void prologue(const float* __restrict__ q,
                                                const float* __restrict__ k,
                                                unsigned short* __restrict__ qb,
                                                unsigned short* __restrict__ kb,
                                                float* __restrict__ lsum) {
    int bid = blockIdx.x;
    if (bid < 4096)      do_cvt(q, qb, bid);
    else if (bid < 8192) do_cvt(k, kb, bid - 4096);
    else                 lsum[(bid - 8192) * 256 + threadIdx.x] = 0.0f;
}
__global__ __launch_bounds__(256) void v_transpose(const float* __restrict__ v,
                                                   unsigned short* __restrict__ vt) {
    __shared__ float tile[64][65];
    do_vt(v, vt, blockIdx.x, tile);
}

// ---------------------------------------------------------------------------
// Pass 1: 256x256 tile, 512 threads (8 waves, 2Mx4N, per-wave 128x64).
// NBUF=3, BK=32. Phase-split K-step: [gldA | vmcnt(6) | bar | ds8+16MFMA | bar |
// gldB | ds4+16MFMA | bar]. Tile issued 2 iters (4 phases) before its gate.
// ---------------------------------------------------------------------------
__global__ __launch_bounds__(512, 2) void pass1(const unsigned short* __restrict__ qb,
                                                const unsigned short* __restrict__ kb,
                                                unsigned short* __restrict__ P,
                                                float* __restrict__ lsum) {
    constexpr int TW = 256 * BK;             // 8192 ushorts = 16 KB / tile
    __shared__ unsigned short ldsA[3 * TW];  // 48 KB
    __shared__ unsigned short ldsB[3 * TW];  // 48 KB

    const int bx = blockIdx.x;
    const int x = bx & 7, j = bx >> 3;       // j in [0,64)
    const int gm = x * 4 + (j & 3);          // [0,32): b*16+mt
    const int nt = j >> 2;                   // [0,16)
    const int b = gm >> 4, mt = gm & 15;
    const int tid = threadIdx.x;
    const int lane = tid & 63, wave = tid >> 6;
    const int l15 = lane & 15, kq = lane >> 4;
    const int wm = (wave & 1) * 128, wn = (wave >> 1) * 64;

    const unsigned short* Ab = qb + ((size_t)b * T + mt * 256) * E;
    const unsigned short* Bb = kb + ((size_t)b * T + nt * 256) * E;

    const unsigned short* ga[2]; const unsigned short* gb[2]; int lo[2];
    #pragma unroll
    for (int i = 0; i < 2; i++) {
        int p = i * 512 + tid;               // 1024 chunks of 16B per 256x32 tile
        int r = p >> 2;
        int qs = (p & 3) ^ ((p >> 3) & 3);   // pre-swizzled global source
        ga[i] = Ab + (size_t)r * E + qs * 8;
        gb[i] = Bb + (size_t)r * E + qs * 8;
        lo[i] = (i * 512 + wave * 64) * 8;   // wave-uniform LDS base
    }
    int aoff[8], boff[4];
    #pragma unroll
    for (int mi = 0; mi < 8; mi++) { int r = wm + mi * 16 + l15; aoff[mi] = (r * 4 + (kq ^ ((r >> 1) & 3))) * 8; }
    #pragma unroll
    for (int ni = 0; ni < 4; ni++) { int r = wn + ni * 16 + l15; boff[ni] = (r * 4 + (kq ^ ((r >> 1) & 3))) * 8; }

    f32x4 acc[8][4];
    #pragma unroll
    for (int i = 0; i < 8; i++)
        #pragma unroll
        for (int jj = 0; jj < 4; jj++) acc[i][jj] = {};

    // prologue: tiles 0,1 -> bufs 0,1 (8 loads outstanding)
    #pragma unroll
    for (int t = 0; t < 2; t++) {
        gld16(ga[0] + t * BK, ldsA + t * TW + lo[0]);
        gld16(ga[1] + t * BK, ldsA + t * TW + lo[1]);
        gld16(gb[0] + t * BK, ldsB + t * TW + lo[0]);
        gld16(gb[1] + t * BK, ldsB + t * TW + lo[1]);
    }

    int c = 0, p2 = 2, pk = 2;
    for (int kt = 0; kt < E / BK; kt++) {
        // stage A-halves of tile kt+2; gate tile kt (kt+1: 4 + kt+2 A: 2 in flight)
        gld16(ga[0] + pk * BK, ldsA + p2 * TW + lo[0]);
        gld16(ga[1] + pk * BK, ldsA + p2 * TW + lo[1]);
        asm volatile("s_waitcnt vmcnt(6)" ::: "memory");
        asm volatile("s_barrier" ::: "memory");

        const unsigned short* A = ldsA + c * TW;
        const unsigned short* B = ldsB + c * TW;
        short8 af[4], bf[4];
        #pragma unroll
        for (int i = 0; i < 4; i++) {
            af[i] = *(const short8*)(A + aoff[i]);
            bf[i] = *(const short8*)(B + boff[i]);
        }
        __builtin_amdgcn_s_setprio(1);
        #pragma unroll
        for (int mi = 0; mi < 4; mi++)
            #pragma unroll
            for (int ni = 0; ni < 4; ni++)
                acc[mi][ni] = __builtin_amdgcn_mfma_f32_16x16x32_bf16(af[mi], bf[ni], acc[mi][ni], 0, 0, 0);
        __builtin_amdgcn_s_setprio(0);
        asm volatile("s_barrier" ::: "memory");

        // phase 2: stage B-halves of tile kt+2, compute lower M-half
        gld16(gb[0] + pk * BK, ldsB + p2 * TW + lo[0]);
        gld16(gb[1] + pk * BK, ldsB + p2 * TW + lo[1]);
        short8 af2[4];
        #pragma unroll
        for (int i = 0; i < 4; i++) af2[i] = *(const short8*)(A + aoff[4 + i]);
        __builtin_amdgcn_s_setprio(1);
        #pragma unroll
        for (int mi = 0; mi < 4; mi++)
            #pragma unroll
            for (int ni = 0; ni < 4; ni++)
                acc[4 + mi][ni] = __builtin_amdgcn_mfma_f32_16x16x32_bf16(af2[mi], bf[ni], acc[4 + mi][ni], 0, 0, 0);
        __builtin_amdgcn_s_setprio(0);
        asm volatile("s_barrier" ::: "memory");

        if (++c == 3) c = 0;
        if (++p2 == 3) p2 = 0;
        if (++pk == E / BK) pk = 0;          // tail reload is harmless
    }

    const int quad = lane >> 4;
    const float sl2 = 0.0625f * 1.44269504089f;
    const int col0 = nt * 256 + wn + l15;
    #pragma unroll
    for (int mi = 0; mi < 8; mi++) {
        #pragma unroll
        for (int r = 0; r < 4; r++) {
            int row = mt * 256 + wm + mi * 16 + quad * 4 + r;
            size_t base = ((size_t)b * T + row) * T + col0;
            float s = 0.0f;
            #pragma unroll
            for (int ni = 0; ni < 4; ni++) {
                float p = exp2f(acc[mi][ni][r] * sl2 - 12.0f);
                P[base + ni * 16] = f2bf(p);
                s += p;
            }
            s += __shfl_xor(s, 1);
            s += __shfl_xor(s, 2);
            s += __shfl_xor(s, 4);
            s += __shfl_xor(s, 8);
            if (l15 == 0) atomicAdd(lsum + b * T + row, s);
        }
    }
}

// ---------------------------------------------------------------------------
// Pass 2: O = (P @ V)/l. 256x128 tile, 512 threads (8 waves, 4Mx2N, per-wave
// 64x64). NBUF=3, BK=32, vmcnt(6) (gate 2 iters after issue), setprio cluster.
// Intensity 87 FLOP/staged-byte vs 64 for the old 128x128 core.
// ---------------------------------------------------------------------------
__global__ __launch_bounds__(512, 2) void pass2(const unsigned short* __restrict__ P,
                                                const unsigned short* __restrict__ vt,
                                                const float* __restrict__ lsum,
                                                float* __restrict__ out) {
    constexpr int TWA = 256 * BK;            // 8192 ushorts
    constexpr int TWB = 128 * BK;            // 4096 ushorts
    __shared__ unsigned short ldsA[3 * TWA]; // 48 KB
    __shared__ unsigned short ldsB[3 * TWB]; // 24 KB

    const int bx = blockIdx.x;
    const int x = bx & 7, j = bx >> 3;       // j in [0,32)
    const int gm = x * 4 + (j & 3);          // [0,32): b*16+mt
    const int nt = j >> 2;                   // [0,8)
    const int b = gm >> 4, mt = gm & 15;
    const int tid = threadIdx.x;
    const int lane = tid & 63, wave = tid >> 6;
    const int l15 = lane & 15, kq = lane >> 4;
    const int wm = (wave & 3) * 64, wn = (wave >> 2) * 64;

    const unsigned short* Ab = P + ((size_t)b * T + mt * 256) * T;
    const unsigned short* Bb = vt + ((size_t)b * E + nt * 128) * T;

    const unsigned short* ga[2]; int lao[2];
    #pragma unroll
    for (int i = 0; i < 2; i++) {
        int p = i * 512 + tid;
        int r = p >> 2;
        int qs = (p & 3) ^ ((p >> 3) & 3);
        ga[i] = Ab + (size_t)r * T + qs * 8;
        lao[i] = (i * 512 + wave * 64) * 8;
    }
    const unsigned short* gb; int lbo;
    {
        int p = tid;                          // 512 chunks for 128x32 B-tile
        int r = p >> 2;
        int qs = (p & 3) ^ ((p >> 3) & 3);
        gb = Bb + (size_t)r * T + qs * 8;
        lbo = (wave * 64) * 8;
    }
    int aoff[4], boff[4];
    #pragma unroll
    for (int mi = 0; mi < 4; mi++) { int r = wm + mi * 16 + l15; aoff[mi] = (r * 4 + (kq ^ ((r >> 1) & 3))) * 8; }
    #pragma unroll
    for (int ni = 0; ni < 4; ni++) { int r = wn + ni * 16 + l15; boff[ni] = (r * 4 + (kq ^ ((r >> 1) & 3))) * 8; }

    f32x4 acc[4][4];
    #pragma unroll
    for (int i = 0; i < 4; i++)
        #pragma unroll
        for (int jj = 0; jj < 4; jj++) acc[i][jj] = {};

    // prologue: tiles 0,1 (6 loads outstanding)
    #pragma unroll
    for (int t = 0; t < 2; t++) {
        gld16(ga[0] + t * BK, ldsA + t * TWA + lao[0]);
        gld16(ga[1] + t * BK, ldsA + t * TWA + lao[1]);
        gld16(gb    + t * BK, ldsB + t * TWB + lbo);
    }

    int c = 0, p2 = 2, pk = 2;
    for (int kt = 0; kt < T / BK; kt++) {
        gld16(ga[0] + pk * BK, ldsA + p2 * TWA + lao[0]);
        gld16(ga[1] + pk * BK, ldsA + p2 * TWA + lao[1]);
        gld16(gb    + pk * BK, ldsB + p2 * TWB + lbo);
        asm volatile("s_waitcnt vmcnt(6)" ::: "memory");   // tile kt landed; kt+1,kt+2 in flight
        asm volatile("s_barrier" ::: "memory");

        const unsigned short* A = ldsA + c * TWA;
        const unsigned short* B = ldsB + c * TWB;
        short8 af[4], bf[4];
        #pragma unroll
        for (int i = 0; i < 4; i++) {
            af[i] = *(const short8*)(A + aoff[i]);
            bf[i] = *(const short8*)(B + boff[i]);
        }
        __builtin_amdgcn_s_setprio(1);
        #pragma unroll
        for (int mi = 0; mi < 4; mi++)
            #pragma unroll
            for (int ni = 0; ni < 4; ni++)
                acc[mi][ni] = __builtin_amdgcn_mfma_f32_16x16x32_bf16(af[mi], bf[ni], acc[mi][ni], 0, 0, 0);
        __builtin_amdgcn_s_setprio(0);
        asm volatile("s_barrier" ::: "memory");

        if (++c == 3) c = 0;
        if (++p2 == 3) p2 = 0;
        if (++pk == T / BK) pk = 0;
    }

    const int quad = lane >> 4;
    const int col0 = nt * 128 + wn + l15;
    #pragma unroll
    for (int mi = 0; mi < 4; mi++) {
        #pragma unroll
        for (int r = 0; r < 4; r++) {
            int row = mt * 256 + wm + mi * 16 + quad * 4 + r;
            float rl = 1.0f / lsum[b * T + row];
            size_t base = ((size_t)b * T + row) * E + col0;
            #pragma unroll
            for (int ni = 0; ni < 4; ni++)
                out[base + ni * 16] = acc[mi][ni][r] * rl;
        }
    }
}

extern "C" void kernel_launch(void* const* d_in, const int* in_sizes, int n_in,
                              void* d_out, int out_size, void* d_ws, size_t ws_size,
                              hipStream_t stream) {
    const float* q = (const float*)d_in[0];
    const float* k = (const float*)d_in[1];
    const float* v = (const float*)d_in[2];
    float* out = (float*)d_out;

    const size_t QK = (size_t)NB * T * E;
    const size_t PSZ = (size_t)NB * T * T;
    float* lsum = (float*)d_ws;
    unsigned short* qbw = (unsigned short*)((char*)d_ws + 32768);
    unsigned short* kbw = qbw + QK;
    unsigned short* Pw  = kbw + QK;

    const size_t full_need = 32768 + (3 * QK + PSZ) * sizeof(unsigned short);

    if (ws_size >= full_need) {
        unsigned short* vtw = Pw + PSZ;
        prep<<<10272, 256, 0, stream>>>(q, k, v, qbw, kbw, vtw, lsum);
        pass1<<<512, 512, 0, stream>>>(qbw, kbw, Pw, lsum);
        pass2<<<256, 512, 0, stream>>>(Pw, vtw, lsum, out);
    } else {
        unsigned short* vtw = qbw;
        prologue<<<8224, 256, 0, stream>>>(q, k, qbw, kbw, lsum);
        pass1<<<512, 512, 0, stream>>>(qbw, kbw, Pw, lsum);
        v_transpose<<<NB * 64 * 16, 256, 0, stream>>>(v, vtw);
        pass2<<<256, 512, 0, stream>>>(Pw, vtw, lsum, out);
    }
}

// Round 2
// 313.027 us; speedup vs baseline: 1.0539x; 1.0539x over previous
//
#include <hip/hip_runtime.h>

using short8  = __attribute__((ext_vector_type(8))) short;
using ushort8 = __attribute__((ext_vector_type(8))) unsigned short;
using f32x4   = __attribute__((ext_vector_type(4))) float;

#define T 4096
#define E 1024
#define NB 2

__device__ __forceinline__ unsigned short f2bf(float f) {
    unsigned int u = __builtin_bit_cast(unsigned int, f);
    u = (u + 0x7FFFu + ((u >> 16) & 1u)) >> 16;
    return (unsigned short)u;
}

__device__ __forceinline__ void gld16(const unsigned short* g, unsigned short* l) {
    __builtin_amdgcn_global_load_lds(
        (__attribute__((address_space(1))) void*)g,
        (__attribute__((address_space(3))) void*)l, 16, 0, 0);
}

__device__ __forceinline__ void do_cvt(const float* __restrict__ src,
                                       unsigned short* __restrict__ dst, int blk) {
    size_t i = ((size_t)blk * 256 + threadIdx.x) * 8;
    float4 f0 = *(const float4*)(src + i);
    float4 f1 = *(const float4*)(src + i + 4);
    ushort8 u;
    u[0]=f2bf(f0.x); u[1]=f2bf(f0.y); u[2]=f2bf(f0.z); u[3]=f2bf(f0.w);
    u[4]=f2bf(f1.x); u[5]=f2bf(f1.y); u[6]=f2bf(f1.z); u[7]=f2bf(f1.w);
    *(ushort8*)(dst + i) = u;
}

__device__ __forceinline__ void do_vt(const float* __restrict__ v,
                                      unsigned short* __restrict__ vt, int id,
                                      float (*tile)[65]) {
    int b   = id / (64 * 16);
    int rem = id % (64 * 16);
    int t0  = (rem / 16) * 64;
    int e0  = (rem % 16) * 64;
    int tid = threadIdx.x;
    int r   = tid >> 2;
    int c0  = (tid & 3) * 16;
    const float* src = v + ((size_t)(b * T + t0 + r)) * E + e0 + c0;
    #pragma unroll
    for (int i = 0; i < 4; i++) {
        float4 f = *(const float4*)(src + i * 4);
        tile[r][c0 + i*4 + 0] = f.x;
        tile[r][c0 + i*4 + 1] = f.y;
        tile[r][c0 + i*4 + 2] = f.z;
        tile[r][c0 + i*4 + 3] = f.w;
    }
    __syncthreads();
    int er = tid >> 2;
    #pragma unroll
    for (int ch = 0; ch < 2; ch++) {
        int tl = (tid & 3) * 16 + ch * 8;
        ushort8 u;
        #pragma unroll
        for (int j = 0; j < 8; j++) u[j] = f2bf(tile[tl + j][er]);
        *(ushort8*)(vt + ((size_t)(b * E + e0 + er)) * T + t0 + tl) = u;
    }
}

// fused prep: [0,4096) q | [4096,8192) k | [8192,10240) v-transpose | [10240,10272) zero lsum
__global__ __launch_bounds__(256) void prep(const float* __restrict__ q,
                                            const float* __restrict__ k,
                                            const float* __restrict__ v,
                                            unsigned short* __restrict__ qb,
                                            unsigned short* __restrict__ kb,
                                            unsigned short* __restrict__ vt,
                                            float* __restrict__ lsum) {
    __shared__ float tile[64][65];
    int bid = blockIdx.x;
    if (bid < 4096)        do_cvt(q, qb, bid);
    else if (bid < 8192)   do_cvt(k, kb, bid - 4096);
    else if (bid < 10240)  do_vt(v, vt, bid - 8192, tile);
    else                   lsum[(bid - 10240) * 256 + threadIdx.x] = 0.0f;
}

// fallback pieces (aliased-ws path)
__global__ __launch_bounds__(256) void prologue(const float* __restrict__ q,
                                                const float* __restrict__ k,
                                                unsigned short* __restrict__ qb,
                                                unsigned short* __restrict__ kb,
                                                float* __restrict__ lsum) {
    int bid = blockIdx.x;
    if (bid < 4096)      do_cvt(q, qb, bid);
    else if (bid < 8192) do_cvt(k, kb, bid - 4096);
    else                 lsum[(bid - 8192) * 256 + threadIdx.x] = 0.0f;
}
__global__ __launch_bounds__(256) void v_transpose(const float* __restrict__ v,
                                                   unsigned short* __restrict__ vt) {
    __shared__ float tile[64][65];
    do_vt(v, vt, blockIdx.x, tile);
}

// ---------------------------------------------------------------------------
// Unified 128x128xBK64 core. 256 threads (4 waves, 2Mx2N, per-wave 64x64).
// NBUF=2, 64 KB LDS -> 2 blocks/CU (the cross-block overlap round-1 lost).
// 32 MFMA/wave per barrier pair (2x round-0) = half the gate overhead.
// 8-way XOR swizzle (chunk ^= row&7): pre-swizzled global source + swizzled
// ds_read offsets; 2-way residual conflict is free.
// vmcnt(8): issue next tile's 8 loads, wait for current tile, next in flight.
// ---------------------------------------------------------------------------
template <int KITERS>
__device__ __forceinline__ void gemm_core64(const unsigned short* Abase, int apitch,
                                            const unsigned short* Bbase, int bpitch,
                                            unsigned short* ldsA, unsigned short* ldsB,
                                            int tid, f32x4 (&acc)[4][4]) {
    constexpr int TILE64 = 128 * 64;         // 8192 ushorts = 16 KB
    const int lane = tid & 63, wave = tid >> 6;
    const int l15 = lane & 15, kq = lane >> 4;
    const int wm = (wave & 1) * 64, wn = (wave >> 1) * 64;

    int goA[4], goB[4], lo[4];
    #pragma unroll
    for (int i = 0; i < 4; i++) {
        int p = i * 256 + tid;               // 1024 chunks of 16B per 128x64 tile
        int r = p >> 3, s = p & 7;
        int sw = s ^ (r & 7);                // inverse-swizzled global chunk
        goA[i] = r * apitch + sw * 8;
        goB[i] = r * bpitch + sw * 8;
        lo[i] = (i * 256 + wave * 64) * 8;   // wave-uniform LDS base (HW adds lane*16B)
    }
    int aoff[2][4], boff[2][4];
    #pragma unroll
    for (int mi = 0; mi < 4; mi++) {
        int r = wm + mi * 16 + l15;
        aoff[0][mi] = (r * 8 + (kq ^ (r & 7))) * 8;
        aoff[1][mi] = (r * 8 + ((kq ^ 4) ^ (r & 7))) * 8;
        int rn = wn + mi * 16 + l15;
        boff[0][mi] = (rn * 8 + (kq ^ (rn & 7))) * 8;
        boff[1][mi] = (rn * 8 + ((kq ^ 4) ^ (rn & 7))) * 8;
    }

    // prologue: tile 0 -> buffer 0 (8 loads outstanding)
    #pragma unroll
    for (int i = 0; i < 4; i++) gld16(Abase + goA[i], ldsA + lo[i]);
    #pragma unroll
    for (int i = 0; i < 4; i++) gld16(Bbase + goB[i], ldsB + lo[i]);

    int cbuf = 0;
    for (int kt = 0; kt < KITERS; kt++) {
        int pk = (kt + 1 < KITERS) ? (kt + 1) : 0;   // tail reload is harmless
        int ob = cbuf ^ 1;
        asm volatile("s_barrier" ::: "memory");      // all waves done reading buf ob
        #pragma unroll
        for (int i = 0; i < 4; i++) gld16(Abase + goA[i] + pk * 64, ldsA + ob * TILE64 + lo[i]);
        #pragma unroll
        for (int i = 0; i < 4; i++) gld16(Bbase + goB[i] + pk * 64, ldsB + ob * TILE64 + lo[i]);
        asm volatile("s_waitcnt vmcnt(8)" ::: "memory");  // tile kt landed; kt+1 in flight
        asm volatile("s_barrier" ::: "memory");

        const unsigned short* A = ldsA + cbuf * TILE64;
        const unsigned short* B = ldsB + cbuf * TILE64;
        #pragma unroll
        for (int ks = 0; ks < 2; ks++) {
            short8 af[4], bf[4];
            #pragma unroll
            for (int i = 0; i < 4; i++) {
                af[i] = *(const short8*)(A + aoff[ks][i]);
                bf[i] = *(const short8*)(B + boff[ks][i]);
            }
            #pragma unroll
            for (int mi = 0; mi < 4; mi++)
                #pragma unroll
                for (int ni = 0; ni < 4; ni++)
                    acc[mi][ni] = __builtin_amdgcn_mfma_f32_16x16x32_bf16(af[mi], bf[ni], acc[mi][ni], 0, 0, 0);
        }
        cbuf = ob;
    }
}

// Pass 1: P = exp2(scale*log2e*(Q K^T) - 12) [bf16], lsum += row sums [fp32]
// 128x128 tile, 2048 blocks. XCD swizzle: 8 row-tiles x 32 nt per XCD.
__global__ __launch_bounds__(256, 2) void pass1(const unsigned short* __restrict__ qb,
                                                const unsigned short* __restrict__ kb,
                                                unsigned short* __restrict__ P,
                                                float* __restrict__ lsum) {
    constexpr int TILE64 = 128 * 64;
    __shared__ unsigned short ldsA[2 * TILE64];  // 32 KB
    __shared__ unsigned short ldsB[2 * TILE64];  // 32 KB

    const int bx = blockIdx.x;
    const int x = bx & 7, j = bx >> 3;       // j in [0,256)
    const int rt = x * 8 + (j >> 5);         // [0,64): b*32+mt
    const int nt = j & 31;                   // [0,32)
    const int b = rt >> 5, mt = rt & 31;
    const int tid = threadIdx.x;

    f32x4 acc[4][4];
    #pragma unroll
    for (int i = 0; i < 4; i++)
        #pragma unroll
        for (int jj = 0; jj < 4; jj++) acc[i][jj] = {};

    gemm_core64<E / 64>(qb + ((size_t)b * T + mt * 128) * E, E,
                        kb + ((size_t)b * T + nt * 128) * E, E,
                        ldsA, ldsB, tid, acc);

    const int lane = tid & 63, wave = tid >> 6;
    const int wm = (wave & 1) * 64, wn = (wave >> 1) * 64;
    const int quad = lane >> 4, l15 = lane & 15;
    const float sl2 = 0.0625f * 1.44269504089f;
    const int col0 = nt * 128 + wn + l15;

    #pragma unroll
    for (int mi = 0; mi < 4; mi++) {
        #pragma unroll
        for (int r = 0; r < 4; r++) {
            int row = mt * 128 + wm + mi * 16 + quad * 4 + r;
            size_t base = ((size_t)b * T + row) * T + col0;
            float s = 0.0f;
            #pragma unroll
            for (int ni = 0; ni < 4; ni++) {
                float p = exp2f(acc[mi][ni][r] * sl2 - 12.0f);
                P[base + ni * 16] = f2bf(p);
                s += p;
            }
            s += __shfl_xor(s, 1);
            s += __shfl_xor(s, 2);
            s += __shfl_xor(s, 4);
            s += __shfl_xor(s, 8);
            if (l15 == 0) atomicAdd(lsum + b * T + row, s);
        }
    }
}

// Pass 2: O = (P @ V) / l ; B operand = VT [b][e][t]
__global__ __launch_bounds__(256, 2) void pass2(const unsigned short* __restrict__ P,
                                                const unsigned short* __restrict__ vt,
                                                const float* __restrict__ lsum,
                                                float* __restrict__ out) {
    constexpr int TILE64 = 128 * 64;
    __shared__ unsigned short ldsA[2 * TILE64];  // 32 KB
    __shared__ unsigned short ldsB[2 * TILE64];  // 32 KB

    const int bx = blockIdx.x;
    const int x = bx & 7, j = bx >> 3;       // j in [0,64)
    const int gm = x * 8 + (j & 7);          // [0,64): b*32+mt
    const int nt = j >> 3;                   // [0,8)
    const int b = gm >> 5, mt = gm & 31;
    const int tid = threadIdx.x;

    f32x4 acc[4][4];
    #pragma unroll
    for (int i = 0; i < 4; i++)
        #pragma unroll
        for (int jj = 0; jj < 4; jj++) acc[i][jj] = {};

    gemm_core64<T / 64>(P + ((size_t)b * T + mt * 128) * T, T,
                        vt + ((size_t)b * E + nt * 128) * T, T,
                        ldsA, ldsB, tid, acc);

    const int lane = tid & 63, wave = tid >> 6;
    const int wm = (wave & 1) * 64, wn = (wave >> 1) * 64;
    const int quad = lane >> 4, l15 = lane & 15;
    const int col0 = nt * 128 + wn + l15;

    #pragma unroll
    for (int mi = 0; mi < 4; mi++) {
        #pragma unroll
        for (int r = 0; r < 4; r++) {
            int row = mt * 128 + wm + mi * 16 + quad * 4 + r;
            float rl = 1.0f / lsum[b * T + row];
            size_t base = ((size_t)b * T + row) * E + col0;
            #pragma unroll
            for (int ni = 0; ni < 4; ni++)
                out[base + ni * 16] = acc[mi][ni][r] * rl;
        }
    }
}

extern "C" void kernel_launch(void* const* d_in, const int* in_sizes, int n_in,
                              void* d_out, int out_size, void* d_ws, size_t ws_size,
                              hipStream_t stream) {
    const float* q = (const float*)d_in[0];
    const float* k = (const float*)d_in[1];
    const float* v = (const float*)d_in[2];
    float* out = (float*)d_out;

    const size_t QK = (size_t)NB * T * E;
    const size_t PSZ = (size_t)NB * T * T;
    float* lsum = (float*)d_ws;
    unsigned short* qbw = (unsigned short*)((char*)d_ws + 32768);
    unsigned short* kbw = qbw + QK;
    unsigned short* Pw  = kbw + QK;

    const size_t full_need = 32768 + (3 * QK + PSZ) * sizeof(unsigned short);

    if (ws_size >= full_need) {
        unsigned short* vtw = Pw + PSZ;
        prep<<<10272, 256, 0, stream>>>(q, k, v, qbw, kbw, vtw, lsum);
        pass1<<<2048, 256, 0, stream>>>(qbw, kbw, Pw, lsum);
        pass2<<<512, 256, 0, stream>>>(Pw, vtw, lsum, out);
    } else {
        unsigned short* vtw = qbw;
        prologue<<<8224, 256, 0, stream>>>(q, k, qbw, kbw, lsum);
        pass1<<<2048, 256, 0, stream>>>(qbw, kbw, Pw, lsum);
        v_transpose<<<NB * 64 * 16, 256, 0, stream>>>(v, vtw);
        pass2<<<512, 256, 0, stream>>>(Pw, vtw, lsum, out);
    }
}

// Round 3
// 292.805 us; speedup vs baseline: 1.1267x; 1.0691x over previous
//
#include <hip/hip_runtime.h>

using short8  = __attribute__((ext_vector_type(8))) short;
using ushort8 = __attribute__((ext_vector_type(8))) unsigned short;
using f32x4   = __attribute__((ext_vector_type(4))) float;

#define T 4096
#define E 1024
#define NB 2

__device__ __forceinline__ unsigned short f2bf(float f) {
    unsigned int u = __builtin_bit_cast(unsigned int, f);
    u = (u + 0x7FFFu + ((u >> 16) & 1u)) >> 16;
    return (unsigned short)u;
}

__device__ __forceinline__ void gld16(const unsigned short* g, unsigned short* l) {
    __builtin_amdgcn_global_load_lds(
        (__attribute__((address_space(1))) void*)g,
        (__attribute__((address_space(3))) void*)l, 16, 0, 0);
}

__device__ __forceinline__ void do_cvt(const float* __restrict__ src,
                                       unsigned short* __restrict__ dst, int blk) {
    size_t i = ((size_t)blk * 256 + threadIdx.x) * 8;
    float4 f0 = *(const float4*)(src + i);
    float4 f1 = *(const float4*)(src + i + 4);
    ushort8 u;
    u[0]=f2bf(f0.x); u[1]=f2bf(f0.y); u[2]=f2bf(f0.z); u[3]=f2bf(f0.w);
    u[4]=f2bf(f1.x); u[5]=f2bf(f1.y); u[6]=f2bf(f1.z); u[7]=f2bf(f1.w);
    *(ushort8*)(dst + i) = u;
}

__device__ __forceinline__ void do_vt(const float* __restrict__ v,
                                      unsigned short* __restrict__ vt, int id,
                                      float (*tile)[65]) {
    int b   = id / (64 * 16);
    int rem = id % (64 * 16);
    int t0  = (rem / 16) * 64;
    int e0  = (rem % 16) * 64;
    int tid = threadIdx.x;
    int r   = tid >> 2;
    int c0  = (tid & 3) * 16;
    const float* src = v + ((size_t)(b * T + t0 + r)) * E + e0 + c0;
    #pragma unroll
    for (int i = 0; i < 4; i++) {
        float4 f = *(const float4*)(src + i * 4);
        tile[r][c0 + i*4 + 0] = f.x;
        tile[r][c0 + i*4 + 1] = f.y;
        tile[r][c0 + i*4 + 2] = f.z;
        tile[r][c0 + i*4 + 3] = f.w;
    }
    __syncthreads();
    int er = tid >> 2;
    #pragma unroll
    for (int ch = 0; ch < 2; ch++) {
        int tl = (tid & 3) * 16 + ch * 8;
        ushort8 u;
        #pragma unroll
        for (int j = 0; j < 8; j++) u[j] = f2bf(tile[tl + j][er]);
        *(ushort8*)(vt + ((size_t)(b * E + e0 + er)) * T + t0 + tl) = u;
    }
}

// fused prep: [0,4096) q | [4096,8192) k | [8192,10240) v-transpose | [10240,10272) zero lsum
__global__ __launch_bounds__(256) void prep(const float* __restrict__ q,
                                            const float* __restrict__ k,
                                            const float* __restrict__ v,
                                            unsigned short* __restrict__ qb,
                                            unsigned short* __restrict__ kb,
                                            unsigned short* __restrict__ vt,
                                            float* __restrict__ lsum) {
    __shared__ float tile[64][65];
    int bid = blockIdx.x;
    if (bid < 4096)        do_cvt(q, qb, bid);
    else if (bid < 8192)   do_cvt(k, kb, bid - 4096);
    else if (bid < 10240)  do_vt(v, vt, bid - 8192, tile);
    else                   lsum[(bid - 10240) * 256 + threadIdx.x] = 0.0f;
}

// fallback pieces (aliased-ws path)
__global__ __launch_bounds__(256) void prologue(const float* __restrict__ q,
                                                const float* __restrict__ k,
                                                unsigned short* __restrict__ qb,
                                                unsigned short* __restrict__ kb,
                                                float* __restrict__ lsum) {
    int bid = blockIdx.x;
    if (bid < 4096)      do_cvt(q, qb, bid);
    else if (bid < 8192) do_cvt(k, kb, bid - 4096);
    else                 lsum[(bid - 8192) * 256 + threadIdx.x] = 0.0f;
}
__global__ __launch_bounds__(256) void v_transpose(const float* __restrict__ v,
                                                   unsigned short* __restrict__ vt) {
    __shared__ float tile[64][65];
    do_vt(v, vt, blockIdx.x, tile);
}

// ===========================================================================
// Pass 1: 256x256 tile, 8-phase m201-style schedule.
// 512 thr = 8 waves (2M x 4N), per-wave 128x64. LDS: 4 A-slots + 4 B-slots,
// each 256 rows x 32 k (16 KB) = 128 KB. Slot s = buf(s>>1).ks(s&1).
// Phase: [ds_read 4A(+4B) | stage 1 half (2 gld16) | (vmcnt(4) @ph4,ph8) |
//         barrier | lgkmcnt(0) | setprio(1) 16 MFMA setprio(0) | barrier]
// Stage stream (iter t): ph1:A3<-K(2t+1).ks1  ph2:B3  ph3:A0<-K(2t+2).ks0
//   ph4:B0  ph5:A1<-K(2t+2).ks1  ph6:B1  ph7:A2<-K(2t+3).ks0  ph8:B2
// Every slot drains at a gate >=1 phase before its first read (verified).
// ===========================================================================
#define P1_PHASE(S, MH, LB, STAGE, GATE) do {                                   \
    const unsigned short* A_ = ldsA + (S) * 8192;                               \
    short8 af[4];                                                               \
    _Pragma("unroll") for (int i_ = 0; i_ < 4; i_++)                            \
        af[i_] = *(const short8*)(A_ + aoff[(MH)*4 + i_]);                      \
    if (LB) {                                                                   \
        const unsigned short* B_ = ldsB + (S) * 8192;                           \
        _Pragma("unroll") for (int i_ = 0; i_ < 4; i_++)                        \
            bf[i_] = *(const short8*)(B_ + boff[i_]);                           \
    }                                                                           \
    STAGE                                                                       \
    GATE                                                                        \
    asm volatile("s_barrier" ::: "memory");                                     \
    asm volatile("s_waitcnt lgkmcnt(0)" ::: "memory");                          \
    __builtin_amdgcn_s_setprio(1);                                              \
    _Pragma("unroll") for (int mi_ = 0; mi_ < 4; mi_++)                         \
        _Pragma("unroll") for (int ni_ = 0; ni_ < 4; ni_++)                     \
            acc[(MH)*4 + mi_][ni_] = __builtin_amdgcn_mfma_f32_16x16x32_bf16(   \
                af[mi_], bf[ni_], acc[(MH)*4 + mi_][ni_], 0, 0, 0);             \
    __builtin_amdgcn_s_setprio(0);                                              \
    asm volatile("s_barrier" ::: "memory");                                     \
} while (0)

__global__ __launch_bounds__(512, 1) void pass1(const unsigned short* __restrict__ qb,
                                                const unsigned short* __restrict__ kb,
                                                unsigned short* __restrict__ P,
                                                float* __restrict__ lsum) {
    __shared__ unsigned short ldsA[4 * 8192];   // 64 KB
    __shared__ unsigned short ldsB[4 * 8192];   // 64 KB

    const int bx = blockIdx.x;
    const int x = bx & 7, j = bx >> 3;          // j in [0,64)
    const int gm = x * 4 + (j & 3);             // [0,32): b*16+mt
    const int nt = j >> 2;                      // [0,16)
    const int b = gm >> 4, mt = gm & 15;
    const int tid = threadIdx.x;
    const int lane = tid & 63, wave = tid >> 6;
    const int l15 = lane & 15, kq = lane >> 4;
    const int wm = (wave & 1) * 128, wn = (wave >> 1) * 64;

    const unsigned short* Ab = qb + ((size_t)b * T + mt * 256) * E;
    const unsigned short* Bb = kb + ((size_t)b * T + nt * 256) * E;

    // staging: a slot is 256 rows x 4 chunks of 16B; thread covers 2 chunks.
    const unsigned short* aS[2]; const unsigned short* bS[2]; int lo[2];
    #pragma unroll
    for (int i = 0; i < 2; i++) {
        int p = i * 512 + tid;
        int r = p >> 2, c = p & 3;
        int sw = (c ^ ((r >> 1) & 3)) * 8;      // pre-swizzled global source
        aS[i] = Ab + (size_t)r * E + sw;
        bS[i] = Bb + (size_t)r * E + sw;
        lo[i] = (i * 512 + wave * 64) * 8;      // wave-uniform LDS base
    }
    int aoff[8], boff[4];
    #pragma unroll
    for (int mf = 0; mf < 8; mf++) { int r = wm + mf * 16 + l15; aoff[mf] = (r * 4 + (kq ^ ((r >> 1) & 3))) * 8; }
    #pragma unroll
    for (int nf = 0; nf < 4; nf++) { int r = wn + nf * 16 + l15; boff[nf] = (r * 4 + (kq ^ ((r >> 1) & 3))) * 8; }

    f32x4 acc[8][4];
    #pragma unroll
    for (int i = 0; i < 8; i++)
        #pragma unroll
        for (int jj = 0; jj < 4; jj++) acc[i][jj] = {};

    // prologue: slots 0,1 <- K-tile0 (k=0,32); slot 2 <- K-tile1 ks0 (k=64)
    gld16(aS[0] + 0,  ldsA + 0 * 8192 + lo[0]);  gld16(aS[1] + 0,  ldsA + 0 * 8192 + lo[1]);
    gld16(bS[0] + 0,  ldsB + 0 * 8192 + lo[0]);  gld16(bS[1] + 0,  ldsB + 0 * 8192 + lo[1]);
    gld16(aS[0] + 32, ldsA + 1 * 8192 + lo[0]);  gld16(aS[1] + 32, ldsA + 1 * 8192 + lo[1]);
    gld16(bS[0] + 32, ldsB + 1 * 8192 + lo[0]);  gld16(bS[1] + 32, ldsB + 1 * 8192 + lo[1]);
    gld16(aS[0] + 64, ldsA + 2 * 8192 + lo[0]);  gld16(aS[1] + 64, ldsA + 2 * 8192 + lo[1]);
    gld16(bS[0] + 64, ldsB + 2 * 8192 + lo[0]);  gld16(bS[1] + 64, ldsB + 2 * 8192 + lo[1]);
    asm volatile("s_waitcnt vmcnt(4)" ::: "memory");   // K0 landed; K1.ks0 in flight
    asm volatile("s_barrier" ::: "memory");

    short8 bf[4];
    for (int t = 0; t < 8; t++) {
        const int k1 = (((2 * t + 1) & 15) << 6) + 32;   // K_{2t+1}.ks1
        const int k2 = (((2 * t + 2) & 15) << 6);        // K_{2t+2}
        const int k3 = (((2 * t + 3) & 15) << 6);        // K_{2t+3}
        P1_PHASE(0, 0, 1, { gld16(aS[0]+k1, ldsA+3*8192+lo[0]); gld16(aS[1]+k1, ldsA+3*8192+lo[1]); }, ;);
        P1_PHASE(0, 1, 0, { gld16(bS[0]+k1, ldsB+3*8192+lo[0]); gld16(bS[1]+k1, ldsB+3*8192+lo[1]); }, ;);
        P1_PHASE(1, 0, 1, { gld16(aS[0]+k2, ldsA+0*8192+lo[0]); gld16(aS[1]+k2, ldsA+0*8192+lo[1]); }, ;);
        P1_PHASE(1, 1, 0, { gld16(bS[0]+k2, ldsB+0*8192+lo[0]); gld16(bS[1]+k2, ldsB+0*8192+lo[1]); },
                 asm volatile("s_waitcnt vmcnt(4)" ::: "memory"););
        P1_PHASE(2, 0, 1, { gld16(aS[0]+k2+32, ldsA+1*8192+lo[0]); gld16(aS[1]+k2+32, ldsA+1*8192+lo[1]); }, ;);
        P1_PHASE(2, 1, 0, { gld16(bS[0]+k2+32, ldsB+1*8192+lo[0]); gld16(bS[1]+k2+32, ldsB+1*8192+lo[1]); }, ;);
        P1_PHASE(3, 0, 1, { gld16(aS[0]+k3, ldsA+2*8192+lo[0]); gld16(aS[1]+k3, ldsA+2*8192+lo[1]); }, ;);
        P1_PHASE(3, 1, 0, { gld16(bS[0]+k3, ldsB+2*8192+lo[0]); gld16(bS[1]+k3, ldsB+2*8192+lo[1]); },
                 asm volatile("s_waitcnt vmcnt(4)" ::: "memory"););
    }
    asm volatile("s_waitcnt vmcnt(0)" ::: "memory");   // drain wrapped tail stages

    const int quad = lane >> 4;
    const float sl2 = 0.0625f * 1.44269504089f;
    const int col0 = nt * 256 + wn + l15;
    #pragma unroll
    for (int mf = 0; mf < 8; mf++) {
        #pragma unroll
        for (int r = 0; r < 4; r++) {
            int row = mt * 256 + wm + mf * 16 + quad * 4 + r;
            size_t base = ((size_t)b * T + row) * T + col0;
            float s = 0.0f;
            #pragma unroll
            for (int ni = 0; ni < 4; ni++) {
                float p = exp2f(acc[mf][ni][r] * sl2 - 12.0f);
                P[base + ni * 16] = f2bf(p);
                s += p;
            }
            s += __shfl_xor(s, 1);
            s += __shfl_xor(s, 2);
            s += __shfl_xor(s, 4);
            s += __shfl_xor(s, 8);
            if (l15 == 0) atomicAdd(lsum + b * T + row, s);
        }
    }
}

// ===========================================================================
// Pass 2: O = (P @ V)/l. 256x128 tile, 4-phase schedule.
// 512 thr = 8 waves (4M x 2N), per-wave 64x64. A-slots 256x32 (16 KB) x4,
// B-slots 128x32 (8 KB) x4 = 96 KB. Slot s = buf(s>>1).ks(s&1).
// Phase p consumes A-slot p-1 & B-slot p-1 (16 MFMA).
// Stage stream (iter t): ph1:{A3,B3}<-K(2t+1).ks1  ph2:{A0,B0}<-K(2t+2).ks0
//   ph3:{A1,B1}<-K(2t+2).ks1  ph4:{A2,B2}<-K(2t+3).ks0
// Gates vmcnt(3) @ph2,ph4: every slot drains strictly before its read phase.
// ===========================================================================
#define P2_PHASE(S, STAGE, GATE) do {                                           \
    const unsigned short* A_ = ldsA + (S) * 8192;                               \
    const unsigned short* B_ = ldsB + (S) * 4096;                               \
    short8 af[4], bf[4];                                                        \
    _Pragma("unroll") for (int i_ = 0; i_ < 4; i_++) {                          \
        af[i_] = *(const short8*)(A_ + aoff[i_]);                               \
        bf[i_] = *(const short8*)(B_ + boff[i_]);                               \
    }                                                                           \
    STAGE                                                                       \
    GATE                                                                        \
    asm volatile("s_barrier" ::: "memory");                                     \
    asm volatile("s_waitcnt lgkmcnt(0)" ::: "memory");                          \
    __builtin_amdgcn_s_setprio(1);                                              \
    _Pragma("unroll") for (int mi_ = 0; mi_ < 4; mi_++)                         \
        _Pragma("unroll") for (int ni_ = 0; ni_ < 4; ni_++)                     \
            acc[mi_][ni_] = __builtin_amdgcn_mfma_f32_16x16x32_bf16(            \
                af[mi_], bf[ni_], acc[mi_][ni_], 0, 0, 0);                      \
    __builtin_amdgcn_s_setprio(0);                                              \
    asm volatile("s_barrier" ::: "memory");                                     \
} while (0)

__global__ __launch_bounds__(512, 1) void pass2(const unsigned short* __restrict__ P,
                                                const unsigned short* __restrict__ vt,
                                                const float* __restrict__ lsum,
                                                float* __restrict__ out) {
    __shared__ unsigned short ldsA[4 * 8192];   // 64 KB
    __shared__ unsigned short ldsB[4 * 4096];   // 32 KB

    const int bx = blockIdx.x;
    const int x = bx & 7, j = bx >> 3;          // j in [0,32)
    const int gm = x * 4 + (j & 3);             // [0,32): b*16+mt
    const int nt = j >> 2;                      // [0,8)
    const int b = gm >> 4, mt = gm & 15;
    const int tid = threadIdx.x;
    const int lane = tid & 63, wave = tid >> 6;
    const int l15 = lane & 15, kq = lane >> 4;
    const int wm = (wave & 3) * 64, wn = (wave >> 2) * 64;

    const unsigned short* Ab = P + ((size_t)b * T + mt * 256) * T;
    const unsigned short* Bb = vt + ((size_t)b * E + nt * 128) * T;

    const unsigned short* aS[2]; int lo[2];
    #pragma unroll
    for (int i = 0; i < 2; i++) {
        int p = i * 512 + tid;
        int r = p >> 2, c = p & 3;
        int sw = (c ^ ((r >> 1) & 3)) * 8;
        aS[i] = Ab + (size_t)r * T + sw;
        lo[i] = (i * 512 + wave * 64) * 8;
    }
    const unsigned short* bS; int lob;
    {
        int p = tid;                             // 512 chunks for 128x32 B-slot
        int r = p >> 2, c = p & 3;
        int sw = (c ^ ((r >> 1) & 3)) * 8;
        bS = Bb + (size_t)r * T + sw;
        lob = (wave * 64) * 8;
    }
    int aoff[4], boff[4];
    #pragma unroll
    for (int mf = 0; mf < 4; mf++) { int r = wm + mf * 16 + l15; aoff[mf] = (r * 4 + (kq ^ ((r >> 1) & 3))) * 8; }
    #pragma unroll
    for (int nf = 0; nf < 4; nf++) { int r = wn + nf * 16 + l15; boff[nf] = (r * 4 + (kq ^ ((r >> 1) & 3))) * 8; }

    f32x4 acc[4][4];
    #pragma unroll
    for (int i = 0; i < 4; i++)
        #pragma unroll
        for (int jj = 0; jj < 4; jj++) acc[i][jj] = {};

    // prologue: slot0 <- K0.ks0, slot1 <- K0.ks1, slot2 <- K1.ks0
    gld16(aS[0] + 0,  ldsA + 0 * 8192 + lo[0]);  gld16(aS[1] + 0,  ldsA + 0 * 8192 + lo[1]);
    gld16(bS + 0,  ldsB + 0 * 4096 + lob);
    gld16(aS[0] + 32, ldsA + 1 * 8192 + lo[0]);  gld16(aS[1] + 32, ldsA + 1 * 8192 + lo[1]);
    gld16(bS + 32, ldsB + 1 * 4096 + lob);
    gld16(aS[0] + 64, ldsA + 2 * 8192 + lo[0]);  gld16(aS[1] + 64, ldsA + 2 * 8192 + lo[1]);
    gld16(bS + 64, ldsB + 2 * 4096 + lob);
    asm volatile("s_waitcnt vmcnt(3)" ::: "memory");   // slots 0,1 landed; slot2 in flight
    asm volatile("s_barrier" ::: "memory");

    for (int t = 0; t < 32; t++) {
        const int k1 = (((2 * t + 1) & 63) << 6) + 32;   // K_{2t+1}.ks1
        const int k2 = (((2 * t + 2) & 63) << 6);        // K_{2t+2}
        const int k3 = (((2 * t + 3) & 63) << 6);        // K_{2t+3}
        P2_PHASE(0, { gld16(aS[0]+k1, ldsA+3*8192+lo[0]); gld16(aS[1]+k1, ldsA+3*8192+lo[1]);
                      gld16(bS+k1, ldsB+3*4096+lob); }, ;);
        P2_PHASE(1, { gld16(aS[0]+k2, ldsA+0*8192+lo[0]); gld16(aS[1]+k2, ldsA+0*8192+lo[1]);
                      gld16(bS+k2, ldsB+0*4096+lob); },
                 asm volatile("s_waitcnt vmcnt(3)" ::: "memory"););
        P2_PHASE(2, { gld16(aS[0]+k2+32, ldsA+1*8192+lo[0]); gld16(aS[1]+k2+32, ldsA+1*8192+lo[1]);
                      gld16(bS+k2+32, ldsB+1*4096+lob); }, ;);
        P2_PHASE(3, { gld16(aS[0]+k3, ldsA+2*8192+lo[0]); gld16(aS[1]+k3, ldsA+2*8192+lo[1]);
                      gld16(bS+k3, ldsB+2*4096+lob); },
                 asm volatile("s_waitcnt vmcnt(3)" ::: "memory"););
    }
    asm volatile("s_waitcnt vmcnt(0)" ::: "memory");   // drain wrapped tail stages

    const int quad = lane >> 4;
    const int col0 = nt * 128 + wn + l15;
    #pragma unroll
    for (int mf = 0; mf < 4; mf++) {
        #pragma unroll
        for (int r = 0; r < 4; r++) {
            int row = mt * 256 + wm + mf * 16 + quad * 4 + r;
            float rl = 1.0f / lsum[b * T + row];
            size_t base = ((size_t)b * T + row) * E + col0;
            #pragma unroll
            for (int ni = 0; ni < 4; ni++)
                out[base + ni * 16] = acc[mf][ni][r] * rl;
        }
    }
}

extern "C" void kernel_launch(void* const* d_in, const int* in_sizes, int n_in,
                              void* d_out, int out_size, void* d_ws, size_t ws_size,
                              hipStream_t stream) {
    const float* q = (const float*)d_in[0];
    const float* k = (const float*)d_in[1];
    const float* v = (const float*)d_in[2];
    float* out = (float*)d_out;

    const size_t QK = (size_t)NB * T * E;
    const size_t PSZ = (size_t)NB * T * T;
    float* lsum = (float*)d_ws;
    unsigned short* qbw = (unsigned short*)((char*)d_ws + 32768);
    unsigned short* kbw = qbw + QK;
    unsigned short* Pw  = kbw + QK;

    const size_t full_need = 32768 + (3 * QK + PSZ) * sizeof(unsigned short);

    if (ws_size >= full_need) {
        unsigned short* vtw = Pw + PSZ;
        prep<<<10272, 256, 0, stream>>>(q, k, v, qbw, kbw, vtw, lsum);
        pass1<<<512, 512, 0, stream>>>(qbw, kbw, Pw, lsum);
        pass2<<<256, 512, 0, stream>>>(Pw, vtw, lsum, out);
    } else {
        unsigned short* vtw = qbw;
        prologue<<<8224, 256, 0, stream>>>(q, k, qbw, kbw, lsum);
        pass1<<<512, 512, 0, stream>>>(qbw, kbw, Pw, lsum);
        v_transpose<<<NB * 64 * 16, 256, 0, stream>>>(v, vtw);
        pass2<<<256, 512, 0, stream>>>(Pw, vtw, lsum, out);
    }
}

// Round 4
// 286.810 us; speedup vs baseline: 1.1503x; 1.0209x over previous
//
#include <hip/hip_runtime.h>

using short8  = __attribute__((ext_vector_type(8))) short;
using ushort8 = __attribute__((ext_vector_type(8))) unsigned short;
using f32x4   = __attribute__((ext_vector_type(4))) float;

#define T 4096
#define E 1024
#define NB 2
#define BM 128
#define BN 128
#define BK 32
#define TILE_ELEMS (BM * BK)     // 4096 ushorts = 8 KB (128-row tile)
#define TILE_A_W   (256 * BK)    // 8192 ushorts = 16 KB (256-row tile)

__device__ __forceinline__ unsigned short f2bf(float f) {
    unsigned int u = __builtin_bit_cast(unsigned int, f);
    u = (u + 0x7FFFu + ((u >> 16) & 1u)) >> 16;
    return (unsigned short)u;
}

__device__ __forceinline__ void gld16(const unsigned short* g, unsigned short* l) {
    __builtin_amdgcn_global_load_lds(
        (__attribute__((address_space(1))) void*)g,
        (__attribute__((address_space(3))) void*)l, 16, 0, 0);
}

__device__ __forceinline__ void do_cvt(const float* __restrict__ src,
                                       unsigned short* __restrict__ dst, int blk) {
    size_t i = ((size_t)blk * 256 + threadIdx.x) * 8;
    float4 f0 = *(const float4*)(src + i);
    float4 f1 = *(const float4*)(src + i + 4);
    ushort8 u;
    u[0]=f2bf(f0.x); u[1]=f2bf(f0.y); u[2]=f2bf(f0.z); u[3]=f2bf(f0.w);
    u[4]=f2bf(f1.x); u[5]=f2bf(f1.y); u[6]=f2bf(f1.z); u[7]=f2bf(f1.w);
    *(ushort8*)(dst + i) = u;
}

__device__ __forceinline__ void do_vt(const float* __restrict__ v,
                                      unsigned short* __restrict__ vt, int id,
                                      float (*tile)[65]) {
    int b   = id / (64 * 16);
    int rem = id % (64 * 16);
    int t0  = (rem / 16) * 64;
    int e0  = (rem % 16) * 64;
    int tid = threadIdx.x;
    int r   = tid >> 2;
    int c0  = (tid & 3) * 16;
    const float* src = v + ((size_t)(b * T + t0 + r)) * E + e0 + c0;
    #pragma unroll
    for (int i = 0; i < 4; i++) {
        float4 f = *(const float4*)(src + i * 4);
        tile[r][c0 + i*4 + 0] = f.x;
        tile[r][c0 + i*4 + 1] = f.y;
        tile[r][c0 + i*4 + 2] = f.z;
        tile[r][c0 + i*4 + 3] = f.w;
    }
    __syncthreads();
    int er = tid >> 2;
    #pragma unroll
    for (int ch = 0; ch < 2; ch++) {
        int tl = (tid & 3) * 16 + ch * 8;
        ushort8 u;
        #pragma unroll
        for (int j = 0; j < 8; j++) u[j] = f2bf(tile[tl + j][er]);
        *(ushort8*)(vt + ((size_t)(b * E + e0 + er)) * T + t0 + tl) = u;
    }
}

// fused prep: [0,4096) q | [4096,8192) k | [8192,10240) v-transpose | [10240,10272) zero lsum
__global__ __launch_bounds__(256) void prep(const float* __restrict__ q,
                                            const float* __restrict__ k,
                                            const float* __restrict__ v,
                                            unsigned short* __restrict__ qb,
                                            unsigned short* __restrict__ kb,
                                            unsigned short* __restrict__ vt,
                                            float* __restrict__ lsum) {
    __shared__ float tile[64][65];
    int bid = blockIdx.x;
    if (bid < 4096)        do_cvt(q, qb, bid);
    else if (bid < 8192)   do_cvt(k, kb, bid - 4096);
    else if (bid < 10240)  do_vt(v, vt, bid - 8192, tile);
    else                   lsum[(bid - 10240) * 256 + threadIdx.x] = 0.0f;
}

// fallback pieces (aliased-ws path)
__global__ __launch_bounds__(256) void prologue(const float* __restrict__ q,
                                                const float* __restrict__ k,
                                                unsigned short* __restrict__ qb,
                                                unsigned short* __restrict__ kb,
                                                float* __restrict__ lsum) {
    int bid = blockIdx.x;
    if (bid < 4096)      do_cvt(q, qb, bid);
    else if (bid < 8192) do_cvt(k, kb, bid - 4096);
    else                 lsum[(bid - 8192) * 256 + threadIdx.x] = 0.0f;
}
__global__ __launch_bounds__(256) void v_transpose(const float* __restrict__ v,
                                                   unsigned short* __restrict__ vt) {
    __shared__ float tile[64][65];
    do_vt(v, vt, blockIdx.x, tile);
}

// ---------------------------------------------------------------------------
// Pass-2 core: 128x128xBK64, 256 threads (4 waves, 2Mx2N, per-wave 64x64).
// NBUF=2, 64 KB LDS -> 2 blocks/CU (cross-block overlap hides the gate).
// 32 MFMA/wave per barrier pair. 8-way XOR swizzle, pre-swizzled global
// source + swizzled ds_read offsets. vmcnt(8): current tile landed, next
// tile's 8 loads in flight across the barrier.
// ---------------------------------------------------------------------------
template <int KITERS>
__device__ __forceinline__ void gemm_core64(const unsigned short* Abase, int apitch,
                                            const unsigned short* Bbase, int bpitch,
                                            unsigned short* ldsA, unsigned short* ldsB,
                                            int tid, f32x4 (&acc)[4][4]) {
    constexpr int TILE64 = 128 * 64;         // 8192 ushorts = 16 KB
    const int lane = tid & 63, wave = tid >> 6;
    const int l15 = lane & 15, kq = lane >> 4;
    const int wm = (wave & 1) * 64, wn = (wave >> 1) * 64;

    int goA[4], goB[4], lo[4];
    #pragma unroll
    for (int i = 0; i < 4; i++) {
        int p = i * 256 + tid;               // 1024 chunks of 16B per 128x64 tile
        int r = p >> 3, s = p & 7;
        int sw = s ^ (r & 7);                // inverse-swizzled global chunk
        goA[i] = r * apitch + sw * 8;
        goB[i] = r * bpitch + sw * 8;
        lo[i] = (i * 256 + wave * 64) * 8;   // wave-uniform LDS base (HW adds lane*16B)
    }
    int aoff[2][4], boff[2][4];
    #pragma unroll
    for (int mi = 0; mi < 4; mi++) {
        int r = wm + mi * 16 + l15;
        aoff[0][mi] = (r * 8 + (kq ^ (r & 7))) * 8;
        aoff[1][mi] = (r * 8 + ((kq ^ 4) ^ (r & 7))) * 8;
        int rn = wn + mi * 16 + l15;
        boff[0][mi] = (rn * 8 + (kq ^ (rn & 7))) * 8;
        boff[1][mi] = (rn * 8 + ((kq ^ 4) ^ (rn & 7))) * 8;
    }

    // prologue: tile 0 -> buffer 0 (8 loads outstanding)
    #pragma unroll
    for (int i = 0; i < 4; i++) gld16(Abase + goA[i], ldsA + lo[i]);
    #pragma unroll
    for (int i = 0; i < 4; i++) gld16(Bbase + goB[i], ldsB + lo[i]);

    int cbuf = 0;
    for (int kt = 0; kt < KITERS; kt++) {
        int pk = (kt + 1 < KITERS) ? (kt + 1) : 0;   // tail reload is harmless
        int ob = cbuf ^ 1;
        asm volatile("s_barrier" ::: "memory");      // all waves done reading buf ob
        #pragma unroll
        for (int i = 0; i < 4; i++) gld16(Abase + goA[i] + pk * 64, ldsA + ob * TILE64 + lo[i]);
        #pragma unroll
        for (int i = 0; i < 4; i++) gld16(Bbase + goB[i] + pk * 64, ldsB + ob * TILE64 + lo[i]);
        asm volatile("s_waitcnt vmcnt(8)" ::: "memory");  // tile kt landed; kt+1 in flight
        asm volatile("s_barrier" ::: "memory");

        const unsigned short* A = ldsA + cbuf * TILE64;
        const unsigned short* B = ldsB + cbuf * TILE64;
        #pragma unroll
        for (int ks = 0; ks < 2; ks++) {
            short8 af[4], bf[4];
            #pragma unroll
            for (int i = 0; i < 4; i++) {
                af[i] = *(const short8*)(A + aoff[ks][i]);
                bf[i] = *(const short8*)(B + boff[ks][i]);
            }
            #pragma unroll
            for (int mi = 0; mi < 4; mi++)
                #pragma unroll
                for (int ni = 0; ni < 4; ni++)
                    acc[mi][ni] = __builtin_amdgcn_mfma_f32_16x16x32_bf16(af[mi], bf[ni], acc[mi][ni], 0, 0, 0);
        }
        cbuf = ob;
    }
}

// ---------------------------------------------------------------------------
// Pass-1 core: 256x128xBK32, 512 threads, NBUF=2.
// Intensity 87 FLOP/staged-byte: preserves L2 panel reuse (R2's 128-wide
// pass1 variant over-fetched 143 MB and regressed to 117 us).
// ---------------------------------------------------------------------------
template <int KITERS>
__device__ __forceinline__ void gemm_core_wide(const unsigned short* Abase, int apitch,
                                               const unsigned short* Bbase, int bpitch,
                                               unsigned short* ldsA, unsigned short* ldsB,
                                               int tid, f32x4 (&acc)[4][4]) {
    const int lane = tid & 63, wave = tid >> 6;          // wave 0..7
    const int l15 = lane & 15, kq = lane >> 4;
    const int wm = (wave & 3) * 64, wn = (wave >> 2) * 64;

    const unsigned short* ga[2];
    int lao[2];
    #pragma unroll
    for (int i = 0; i < 2; i++) {
        int p = i * 512 + tid;                            // A: 1024 chunks
        int r = p >> 2;
        int kqw = (p & 3) ^ ((p >> 3) & 3);
        ga[i] = Abase + (size_t)r * apitch + kqw * 8;
        lao[i] = (i * 512 + wave * 64) * 8;
    }
    const unsigned short* gb;
    int lbo;
    {
        int p = tid;                                      // B: 512 chunks
        int r = p >> 2;
        int kqw = (p & 3) ^ ((p >> 3) & 3);
        gb = Bbase + (size_t)r * bpitch + kqw * 8;
        lbo = (wave * 64) * 8;
    }
    int aoff[4], boff[4];
    #pragma unroll
    for (int mi = 0; mi < 4; mi++) {
        int r = wm + mi * 16 + l15;                       // [0,256)
        aoff[mi] = (r * 4 + (kq ^ ((r >> 1) & 3))) * 8;
        int rn = wn + mi * 16 + l15;                      // [0,128)
        boff[mi] = (rn * 4 + (kq ^ ((rn >> 1) & 3))) * 8;
    }

    // prefetch tile 0 -> buffer 0
    gld16(ga[0], ldsA + lao[0]);
    gld16(ga[1], ldsA + lao[1]);
    gld16(gb,    ldsB + lbo);

    int cbuf = 0;
    for (int kt = 0; kt < KITERS; kt++) {
        int nxt = (kt + 1 < KITERS) ? (kt + 1) : 0;       // tail reload is harmless
        int obuf = cbuf ^ 1;
        asm volatile("s_barrier" ::: "memory");           // done computing on obuf
        gld16(ga[0] + nxt * BK, ldsA + obuf * TILE_A_W + lao[0]);
        gld16(ga[1] + nxt * BK, ldsA + obuf * TILE_A_W + lao[1]);
        gld16(gb    + nxt * BK, ldsB + obuf * TILE_ELEMS + lbo);
        asm volatile("s_waitcnt vmcnt(3)" ::: "memory");  // tile kt landed; kt+1 in flight
        asm volatile("s_barrier" ::: "memory");

        const unsigned short* A = ldsA + cbuf * TILE_A_W;
        const unsigned short* B = ldsB + cbuf * TILE_ELEMS;
        short8 af[4], bf[4];
        #pragma unroll
        for (int i = 0; i < 4; i++) {
            af[i] = *(const short8*)(A + aoff[i]);
            bf[i] = *(const short8*)(B + boff[i]);
        }
        #pragma unroll
        for (int mi = 0; mi < 4; mi++)
            #pragma unroll
            for (int ni = 0; ni < 4; ni++)
                acc[mi][ni] = __builtin_amdgcn_mfma_f32_16x16x32_bf16(af[mi], bf[ni], acc[mi][ni], 0, 0, 0);

        cbuf = obuf;
    }
}

// Pass 1: P = exp2(scale*log2e*(Q K^T) - 12) [bf16], lsum += row sums [fp32]
// 256x128 tile, 512 threads. XCD swizzle: 4 row-tiles x 32 nt per XCD.
__global__ __launch_bounds__(512, 2) void pass1(const unsigned short* __restrict__ qb,
                                                const unsigned short* __restrict__ kb,
                                                unsigned short* __restrict__ P,
                                                float* __restrict__ lsum) {
    __shared__ unsigned short ldsA[2 * TILE_A_W];    // 32 KB
    __shared__ unsigned short ldsB[2 * TILE_ELEMS];  // 16 KB
    const int bx = blockIdx.x;
    const int x = bx & 7, j = bx >> 3;               // j in [0,128)
    const int gm = x * 4 + (j & 3);                  // [0,32): b*16+mt
    const int nt = j >> 2;                           // [0,32)
    const int b = gm >> 4, mt = gm & 15;
    const int tid = threadIdx.x;

    f32x4 acc[4][4];
    #pragma unroll
    for (int i = 0; i < 4; i++)
        #pragma unroll
        for (int jj = 0; jj < 4; jj++) acc[i][jj] = {};

    gemm_core_wide<E / BK>(qb + ((size_t)b * T + mt * 256) * E, E,
                           kb + ((size_t)b * T + nt * BN) * E, E,
                           ldsA, ldsB, tid, acc);

    const int lane = tid & 63, wave = tid >> 6;
    const int wm = (wave & 3) * 64, wn = (wave >> 2) * 64;
    const int quad = lane >> 4, l15 = lane & 15;
    const float sl2 = 0.0625f * 1.44269504089f;
    const int col0 = nt * BN + wn + l15;

    #pragma unroll
    for (int mi = 0; mi < 4; mi++) {
        #pragma unroll
        for (int r = 0; r < 4; r++) {
            int row = mt * 256 + wm + mi * 16 + quad * 4 + r;
            size_t base = ((size_t)b * T + row) * T + col0;
            float s = 0.0f;
            #pragma unroll
            for (int ni = 0; ni < 4; ni++) {
                float p = exp2f(acc[mi][ni][r] * sl2 - 12.0f);
                P[base + ni * 16] = f2bf(p);
                s += p;
            }
            s += __shfl_xor(s, 1);
            s += __shfl_xor(s, 2);
            s += __shfl_xor(s, 4);
            s += __shfl_xor(s, 8);
            if (l15 == 0) atomicAdd(lsum + b * T + row, s);
        }
    }
}

// Pass 2: O = (P @ V) / l ; B operand = VT [b][e][t]
__global__ __launch_bounds__(256, 2) void pass2(const unsigned short* __restrict__ P,
                                                const unsigned short* __restrict__ vt,
                                                const float* __restrict__ lsum,
                                                float* __restrict__ out) {
    constexpr int TILE64 = 128 * 64;
    __shared__ unsigned short ldsA[2 * TILE64];  // 32 KB
    __shared__ unsigned short ldsB[2 * TILE64];  // 32 KB

    const int bx = blockIdx.x;
    const int x = bx & 7, j = bx >> 3;       // j in [0,64)
    const int gm = x * 8 + (j & 7);          // [0,64): b*32+mt
    const int nt = j >> 3;                   // [0,8)
    const int b = gm >> 5, mt = gm & 31;
    const int tid = threadIdx.x;

    f32x4 acc[4][4];
    #pragma unroll
    for (int i = 0; i < 4; i++)
        #pragma unroll
        for (int jj = 0; jj < 4; jj++) acc[i][jj] = {};

    gemm_core64<T / 64>(P + ((size_t)b * T + mt * 128) * T, T,
                        vt + ((size_t)b * E + nt * 128) * T, T,
                        ldsA, ldsB, tid, acc);

    const int lane = tid & 63, wave = tid >> 6;
    const int wm = (wave & 1) * 64, wn = (wave >> 1) * 64;
    const int quad = lane >> 4, l15 = lane & 15;
    const int col0 = nt * 128 + wn + l15;

    #pragma unroll
    for (int mi = 0; mi < 4; mi++) {
        #pragma unroll
        for (int r = 0; r < 4; r++) {
            int row = mt * 128 + wm + mi * 16 + quad * 4 + r;
            float rl = 1.0f / lsum[b * T + row];
            size_t base = ((size_t)b * T + row) * E + col0;
            #pragma unroll
            for (int ni = 0; ni < 4; ni++)
                out[base + ni * 16] = acc[mi][ni][r] * rl;
        }
    }
}

extern "C" void kernel_launch(void* const* d_in, const int* in_sizes, int n_in,
                              void* d_out, int out_size, void* d_ws, size_t ws_size,
                              hipStream_t stream) {
    const float* q = (const float*)d_in[0];
    const float* k = (const float*)d_in[1];
    const float* v = (const float*)d_in[2];
    float* out = (float*)d_out;

    const size_t QK = (size_t)NB * T * E;
    const size_t PSZ = (size_t)NB * T * T;
    float* lsum = (float*)d_ws;
    unsigned short* qbw = (unsigned short*)((char*)d_ws + 32768);
    unsigned short* kbw = qbw + QK;
    unsigned short* Pw  = kbw + QK;

    const size_t full_need = 32768 + (3 * QK + PSZ) * sizeof(unsigned short);

    if (ws_size >= full_need) {
        unsigned short* vtw = Pw + PSZ;
        prep<<<10272, 256, 0, stream>>>(q, k, v, qbw, kbw, vtw, lsum);
        pass1<<<1024, 512, 0, stream>>>(qbw, kbw, Pw, lsum);
        pass2<<<512, 256, 0, stream>>>(Pw, vtw, lsum, out);
    } else {
        unsigned short* vtw = qbw;
        prologue<<<8224, 256, 0, stream>>>(q, k, qbw, kbw, lsum);
        pass1<<<1024, 512, 0, stream>>>(qbw, kbw, Pw, lsum);
        v_transpose<<<NB * 64 * 16, 256, 0, stream>>>(v, vtw);
        pass2<<<512, 256, 0, stream>>>(Pw, vtw, lsum, out);
    }
}